// Round 5
// baseline (2773.363 us; speedup 1.0000x reference)
//
#include <hip/hip_runtime.h>
#include <hip/hip_bf16.h>

#define B_    16
#define R_    13
#define N_    392
#define F_    256
#define RN_   (R_*N_)        // 5096
#define M_    (B_*RN_)       // 81536
#define POOL_ 512
#define NCLS_ 200

// ---------------- reduction helpers ----------------
__device__ __forceinline__ float warpMax(float v){
  #pragma unroll
  for (int o = 32; o; o >>= 1) v = fmaxf(v, __shfl_down(v, o));
  return v;
}
__device__ __forceinline__ float warpSum(float v){
  #pragma unroll
  for (int o = 32; o; o >>= 1) v += __shfl_down(v, o);
  return v;
}
__device__ __forceinline__ float blockMax(float v, float* red){
  v = warpMax(v);
  __syncthreads();
  if ((threadIdx.x & 63) == 0) red[threadIdx.x >> 6] = v;
  __syncthreads();
  return fmaxf(fmaxf(red[0], red[1]), fmaxf(red[2], red[3]));
}
__device__ __forceinline__ float blockSum(float v, float* red){
  v = warpSum(v);
  __syncthreads();
  if ((threadIdx.x & 63) == 0) red[threadIdx.x >> 6] = v;
  __syncthreads();
  return red[0] + red[1] + red[2] + red[3];
}
__device__ __forceinline__ float eluf(float v){
  return v > 0.f ? v : (expf(v) - 1.f);
}

// ---------------- GEMM [M,256]@[256,256], optional sigmoid epilogue ----------------
// AMODE 0: A rows are identity-indexed. AMODE 1: logical row (b*N+n)*R+r gathers
// physical x row (b*R+r)*N+n  (the [B,N,R,F] transpose view of x).
template<int AMODE, int ACT>
__global__ __launch_bounds__(256) void gemm256(
    const float* __restrict__ A, const float* __restrict__ W,
    const float* __restrict__ bias, float* __restrict__ out){
  __shared__ float As[16][64];
  __shared__ float Bs[16][64];
  __shared__ int arows[64];
  const int tid = threadIdx.x;
  const int mb = blockIdx.x, nb = blockIdx.y;
  const int ty = tid >> 4, tx = tid & 15;
  const int row0 = mb * 64;

  if (AMODE == 1){
    if (tid < 64){
      const int row = row0 + tid;
      const int b   = row / RN_;
      const int rem = row - b*RN_;
      const int n   = rem / R_;
      const int r   = rem - n*R_;
      arows[tid] = (b*R_ + r)*N_ + n;
    }
    __syncthreads();
  }

  float acc[4][4] = {};
  for (int k0 = 0; k0 < 256; k0 += 16){
    #pragma unroll
    for (int i = 0; i < 4; ++i){
      const int idx = tid + i*256;
      const int m = idx >> 4, kk = idx & 15;
      const int arow = (AMODE == 0) ? (row0 + m) : arows[m];
      As[kk][m] = A[(long)arow*F_ + k0 + kk];
      const int kk2 = idx >> 6, n2 = idx & 63;
      Bs[kk2][n2] = W[(k0 + kk2)*F_ + nb*64 + n2];
    }
    __syncthreads();
    #pragma unroll
    for (int kk = 0; kk < 16; ++kk){
      const float4 av = *(const float4*)&As[kk][ty*4];
      const float4 bv = *(const float4*)&Bs[kk][tx*4];
      acc[0][0] += av.x*bv.x; acc[0][1] += av.x*bv.y; acc[0][2] += av.x*bv.z; acc[0][3] += av.x*bv.w;
      acc[1][0] += av.y*bv.x; acc[1][1] += av.y*bv.y; acc[1][2] += av.y*bv.z; acc[1][3] += av.y*bv.w;
      acc[2][0] += av.z*bv.x; acc[2][1] += av.z*bv.y; acc[2][2] += av.z*bv.z; acc[2][3] += av.z*bv.w;
      acc[3][0] += av.w*bv.x; acc[3][1] += av.w*bv.y; acc[3][2] += av.w*bv.z; acc[3][3] += av.w*bv.w;
    }
    __syncthreads();
  }
  const int col0 = nb*64 + tx*4;
  #pragma unroll
  for (int i = 0; i < 4; ++i){
    const int row = row0 + ty*4 + i;
    float4 o;
    o.x = acc[i][0]; o.y = acc[i][1]; o.z = acc[i][2]; o.w = acc[i][3];
    if (ACT){
      o.x += bias[col0+0]; o.y += bias[col0+1]; o.z += bias[col0+2]; o.w += bias[col0+3];
      o.x = 1.f/(1.f+expf(-o.x)); o.y = 1.f/(1.f+expf(-o.y));
      o.z = 1.f/(1.f+expf(-o.z)); o.w = 1.f/(1.f+expf(-o.w));
    }
    *(float4*)&out[(long)row*F_ + col0] = o;
  }
}

// ---------------- per-graph column sum (APPNP propagation) ----------------
__global__ __launch_bounds__(256) void colsum_k(const float* __restrict__ h1,
    float* __restrict__ S, int nn, int chunk){
  const int g  = blockIdx.x;
  const int n0 = blockIdx.y * chunk;
  const int f  = threadIdx.x;
  const int n1 = min(nn, n0 + chunk);
  const float* base = h1 + (long)g*nn*F_ + f;
  float s = 0.f;
  for (int n = n0; n < n1; ++n) s += base[(long)n*F_];
  atomicAdd(&S[(long)g*F_ + f], s);
}

// ---------------- h = 0.5*(S+h1)/(nn+1) + 0.5*h1 + x ----------------
template<int XMODE>
__global__ __launch_bounds__(256) void combine_k(const float* __restrict__ h1,
    const float* __restrict__ S, const float* __restrict__ x,
    float* __restrict__ h){
  const long t = (long)blockIdx.x*256 + threadIdx.x;   // over M_*64 float4 slots
  const long row = t >> 6;
  const int f4 = (int)(t & 63);
  int g, xrow;
  if (XMODE == 0){ g = (int)(row / N_); xrow = (int)row; }
  else {
    g = (int)(row / R_);
    const int b   = (int)(row / RN_);
    const int rem = (int)(row - (long)b*RN_);
    const int n   = rem / R_;
    const int r   = rem - n*R_;
    xrow = (b*R_ + r)*N_ + n;
  }
  const float inv = (XMODE == 0) ? (1.f/(N_+1)) : (1.f/(R_+1));
  const float4 h1v = *(const float4*)&h1[row*F_ + f4*4];
  const float4 Sv  = *(const float4*)&S[(long)g*F_ + f4*4];
  const float4 xv  = *(const float4*)&x[(long)xrow*F_ + f4*4];
  float4 o;
  o.x = 0.5f*(Sv.x + h1v.x)*inv + 0.5f*h1v.x + xv.x;
  o.y = 0.5f*(Sv.y + h1v.y)*inv + 0.5f*h1v.y + xv.y;
  o.z = 0.5f*(Sv.z + h1v.z)*inv + 0.5f*h1v.z + xv.z;
  o.w = 0.5f*(Sv.w + h1v.w)*inv + 0.5f*h1v.w + xv.w;
  *(float4*)&h[row*F_ + f4*4] = o;
}

// ---------------- per-node attention scalars s,t ----------------
__global__ __launch_bounds__(256) void st_k(const float* __restrict__ xk,
    const float* __restrict__ a_self, const float* __restrict__ a_neigh,
    float* __restrict__ sv, float* __restrict__ tv){
  const int lane = threadIdx.x & 63;
  const int wid  = threadIdx.x >> 6;
  const long row = (long)blockIdx.x*4 + wid;
  const float4 v  = ((const float4*)(xk + row*F_))[lane];
  const float4 as = ((const float4*)a_self)[lane];
  const float4 an = ((const float4*)a_neigh)[lane];
  float s = v.x*as.x + v.y*as.y + v.z*as.z + v.w*as.w;
  float t = v.x*an.x + v.y*an.y + v.z*an.z + v.w*an.w;
  #pragma unroll
  for (int o = 32; o; o >>= 1){ s += __shfl_down(s, o); t += __shfl_down(t, o); }
  if (lane == 0){ sv[row] = s; tv[row] = t; }
}

// ---------------- intra-ROI attention: graphs of 392 nodes ----------------
// Writes x2 IN PLACE over h (row g*N+m): each row is read once (residual) then
// overwritten by the same lanes — no cross-thread hazard.
__global__ __launch_bounds__(256) void attn_intra_k(
    const float* __restrict__ xk, const float* __restrict__ sv,
    const float* __restrict__ tv, const float* __restrict__ bg,
    float* __restrict__ hx2){
  const int g  = blockIdx.y;
  const int m0 = blockIdx.x * 32;
  const int tid = threadIdx.x;
  __shared__ float t_lds[N_];
  __shared__ float w_lds[32][N_];
  __shared__ float invr[32];
  __shared__ float red[4];

  for (int n = tid; n < N_; n += 256) t_lds[n] = tv[(long)g*N_ + n];
  __syncthreads();
  float tl = -1e30f;
  for (int n = tid; n < N_; n += 256) tl = fmaxf(tl, t_lds[n]);
  const float tmax = blockMax(tl, red);

  const int nrows = min(32, N_ - m0);
  for (int j = 0; j < nrows; ++j){
    const float sm = sv[(long)g*N_ + m0 + j];
    float zm = sm + tmax; zm = zm > 0.f ? zm : 0.2f*zm;   // lrelu monotone -> row max
    float loc = 0.f;
    for (int n = tid; n < N_; n += 256){
      float z = sm + t_lds[n];
      z = z > 0.f ? z : 0.2f*z;
      const float e = expf(z - zm);
      w_lds[j][n] = e;
      loc += e;
    }
    const float tot = blockSum(loc, red);
    if (tid == 0) invr[j] = 1.f / tot;
  }
  __syncthreads();

  const int ty = tid >> 6, tx = tid & 63;
  float4 acc[8];
  #pragma unroll
  for (int j = 0; j < 8; ++j) acc[j] = make_float4(0.f,0.f,0.f,0.f);
  const float4* xkg = (const float4*)(xk + (long)g*N_*F_);
  for (int n = 0; n < N_; ++n){
    const float4 xv = xkg[n*64 + tx];
    #pragma unroll
    for (int j = 0; j < 8; ++j){
      const float w = w_lds[ty*8 + j][n];
      acc[j].x += w*xv.x; acc[j].y += w*xv.y; acc[j].z += w*xv.z; acc[j].w += w*xv.w;
    }
  }
  const float4 bgv = ((const float4*)bg)[tx];
  #pragma unroll
  for (int j = 0; j < 8; ++j){
    const int m = m0 + ty*8 + j;
    if (m < N_){
      const float iv = invr[ty*8 + j];
      float4* hp = (float4*)(hx2 + ((long)g*N_ + m)*F_);
      const float4 hv = hp[tx];
      float4 o;
      o.x = eluf(acc[j].x*iv + bgv.x) + hv.x;
      o.y = eluf(acc[j].y*iv + bgv.y) + hv.y;
      o.z = eluf(acc[j].z*iv + bgv.z) + hv.z;
      o.w = eluf(acc[j].w*iv + bgv.w) + hv.w;
      hp[tx] = o;
    }
  }
}

// ---------------- inter-ROI attention: graphs of 13 nodes (in-place over h) ----------------
__global__ __launch_bounds__(256) void attn_inter_k(
    const float* __restrict__ xk, const float* __restrict__ sv,
    const float* __restrict__ tv, const float* __restrict__ bg,
    float* __restrict__ hx2){
  const int g = blockIdx.x;
  const int tid = threadIdx.x;
  __shared__ float w_lds[R_][R_];
  __shared__ float invr[R_];
  __shared__ float st[R_], tt[R_];
  if (tid < R_){ st[tid] = sv[(long)g*R_ + tid]; tt[tid] = tv[(long)g*R_ + tid]; }
  __syncthreads();
  if (tid < R_){
    const float sm = st[tid];
    float z[R_];
    float zm = -1e30f;
    #pragma unroll
    for (int n = 0; n < R_; ++n){
      float zz = sm + tt[n];
      zz = zz > 0.f ? zz : 0.2f*zz;
      z[n] = zz;
      zm = fmaxf(zm, zz);
    }
    float sum = 0.f;
    #pragma unroll
    for (int n = 0; n < R_; ++n){
      const float e = expf(z[n] - zm);
      w_lds[tid][n] = e;
      sum += e;
    }
    invr[tid] = 1.f/sum;
  }
  __syncthreads();
  float acc[R_] = {};
  const float* xkg = xk + (long)g*R_*F_;
  #pragma unroll
  for (int n = 0; n < R_; ++n){
    const float xv = xkg[n*F_ + tid];
    #pragma unroll
    for (int m = 0; m < R_; ++m) acc[m] += w_lds[m][n]*xv;
  }
  const float bgv = bg[tid];
  #pragma unroll
  for (int m = 0; m < R_; ++m){
    const long row = (long)g*R_ + m;
    const float hv = hx2[row*F_ + tid];
    hx2[row*F_ + tid] = eluf(acc[m]*invr[m] + bgv) + hv;
  }
}

// ---------------- global attention pooling (dual GEMM + accumulate) ----------------
// Called once per path; pooling is row-separable so accumulation order is free.
// grid (ceil(RN/64) j-tiles, 8 c-tiles, 16 batches)
__global__ __launch_bounds__(256) void pool_k(const float* __restrict__ x2,
    const float* __restrict__ wa, const float* __restrict__ ba,
    const float* __restrict__ wf, const float* __restrict__ bf,
    float* __restrict__ pooled, int nrows){
  __shared__ float Xs[16][64];
  __shared__ float Was[16][64];
  __shared__ float Wfs[16][64];
  __shared__ float part[16][64];
  const int jt = blockIdx.x, ct = blockIdx.y, b = blockIdx.z;
  const int tid = threadIdx.x;
  const int ty = tid >> 4, tx = tid & 15;
  const int j0 = jt*64, c0 = ct*64;
  float accA[4][4] = {}, accF[4][4] = {};
  const float* xb = x2 + (long)b*nrows*F_;
  for (int k0 = 0; k0 < 256; k0 += 16){
    #pragma unroll
    for (int i = 0; i < 4; ++i){
      const int idx = tid + i*256;
      const int m = idx >> 4, kk = idx & 15;
      const int j = j0 + m;
      Xs[kk][m] = (j < nrows) ? xb[(long)j*F_ + k0 + kk] : 0.f;
      const int kk2 = idx >> 6, n2 = idx & 63;
      Was[kk2][n2] = wa[(k0+kk2)*POOL_ + c0 + n2];
      Wfs[kk2][n2] = wf[(k0+kk2)*POOL_ + c0 + n2];
    }
    __syncthreads();
    #pragma unroll
    for (int kk = 0; kk < 16; ++kk){
      const float4 xv = *(const float4*)&Xs[kk][ty*4];
      const float4 av = *(const float4*)&Was[kk][tx*4];
      const float4 fv = *(const float4*)&Wfs[kk][tx*4];
      accA[0][0]+=xv.x*av.x; accA[0][1]+=xv.x*av.y; accA[0][2]+=xv.x*av.z; accA[0][3]+=xv.x*av.w;
      accA[1][0]+=xv.y*av.x; accA[1][1]+=xv.y*av.y; accA[1][2]+=xv.y*av.z; accA[1][3]+=xv.y*av.w;
      accA[2][0]+=xv.z*av.x; accA[2][1]+=xv.z*av.y; accA[2][2]+=xv.z*av.z; accA[2][3]+=xv.z*av.w;
      accA[3][0]+=xv.w*av.x; accA[3][1]+=xv.w*av.y; accA[3][2]+=xv.w*av.z; accA[3][3]+=xv.w*av.w;
      accF[0][0]+=xv.x*fv.x; accF[0][1]+=xv.x*fv.y; accF[0][2]+=xv.x*fv.z; accF[0][3]+=xv.x*fv.w;
      accF[1][0]+=xv.y*fv.x; accF[1][1]+=xv.y*fv.y; accF[1][2]+=xv.y*fv.z; accF[1][3]+=xv.y*fv.w;
      accF[2][0]+=xv.z*fv.x; accF[2][1]+=xv.z*fv.y; accF[2][2]+=xv.z*fv.z; accF[2][3]+=xv.z*fv.w;
      accF[3][0]+=xv.w*fv.x; accF[3][1]+=xv.w*fv.y; accF[3][2]+=xv.w*fv.z; accF[3][3]+=xv.w*fv.w;
    }
    __syncthreads();
  }
  float csum[4] = {0.f,0.f,0.f,0.f};
  #pragma unroll
  for (int i = 0; i < 4; ++i){
    const int j = j0 + ty*4 + i;
    if (j < nrows){
      #pragma unroll
      for (int jj = 0; jj < 4; ++jj){
        const int c = c0 + tx*4 + jj;
        const float a = accA[i][jj] + ba[c];
        const float f = accF[i][jj] + bf[c];
        csum[jj] += f / (1.f + expf(-a));   // sigmoid(a)*f
      }
    }
  }
  #pragma unroll
  for (int jj = 0; jj < 4; ++jj) part[ty][tx*4+jj] = csum[jj];
  __syncthreads();
  if (tid < 64){
    float s = 0.f;
    #pragma unroll
    for (int t = 0; t < 16; ++t) s += part[t][tid];
    atomicAdd(&pooled[(long)b*POOL_ + c0 + tid], s);
  }
}

// ---------------- BN + classifier + softmax ----------------
__global__ __launch_bounds__(256) void final_k(const float* __restrict__ pooled,
    const float* __restrict__ gamma, const float* __restrict__ beta,
    const float* __restrict__ mean, const float* __restrict__ var,
    const float* __restrict__ wout, const float* __restrict__ bout,
    float* __restrict__ out){
  const int b = blockIdx.x, tid = threadIdx.x;
  __shared__ float bn[POOL_];
  __shared__ float red[4];
  for (int c = tid; c < POOL_; c += 256){
    const float p = pooled[(long)b*POOL_ + c];
    bn[c] = (p - mean[c]) * rsqrtf(var[c] + 1e-3f) * gamma[c] + beta[c];
  }
  __syncthreads();
  float logit = -3.0e38f;
  if (tid < NCLS_){
    float s = bout[tid];
    for (int k = 0; k < POOL_; ++k) s += bn[k]*wout[k*NCLS_ + tid];
    logit = s;
  }
  const float mx = blockMax(logit, red);
  float e = (tid < NCLS_) ? expf(logit - mx) : 0.f;
  const float tot = blockSum(e, red);
  if (tid < NCLS_) out[(long)b*NCLS_ + tid] = e / tot;
}

// ---------------- launcher ----------------
extern "C" void kernel_launch(void* const* d_in, const int* in_sizes, int n_in,
                              void* d_out, int out_size, void* d_ws, size_t ws_size,
                              hipStream_t stream){
  const float* x       = (const float*)d_in[0];
  const float* w_mlp   = (const float*)d_in[1];
  const float* b_mlp   = (const float*)d_in[2];
  const float* k_gat   = (const float*)d_in[3];
  const float* a_self  = (const float*)d_in[4];
  const float* a_neigh = (const float*)d_in[5];
  const float* b_gat   = (const float*)d_in[6];
  const float* wf_pool = (const float*)d_in[7];
  const float* bf_pool = (const float*)d_in[8];
  const float* wa_pool = (const float*)d_in[9];
  const float* ba_pool = (const float*)d_in[10];
  const float* bn_g    = (const float*)d_in[11];
  const float* bn_b    = (const float*)d_in[12];
  const float* bn_m    = (const float*)d_in[13];
  const float* bn_v    = (const float*)d_in[14];
  const float* w_out   = (const float*)d_in[15];
  const float* b_out   = (const float*)d_in[16];
  float* out = (float*)d_out;

  // Workspace layout (174 MB total; was 341 MB — suspected cause of the R4 fault):
  //   bufA [M,F]   h1 / xk
  //   bufH [M,F]   h, then x2 in place
  //   S    [B*N,F] APPNP column sums (shared by both paths, re-zeroed)
  //   sbuf,tbuf [M] attention scalars;  pooled [B,512]
  float* ws = (float*)d_ws;
  const long MF = (long)M_ * F_;                 // 20,873,216
  float* bufA   = ws;
  float* bufH   = bufA + MF;
  float* Sbuf   = bufH + MF;                     // B*N*F = 1,605,632
  float* sbuf   = Sbuf + (long)B_*N_*F_;
  float* tbuf   = sbuf + M_;
  float* pooled = tbuf + M_;                     // B*512

  hipMemsetAsync(pooled, 0, (size_t)B_*POOL_*sizeof(float), stream);

  const dim3 gemm_grid(M_/64, F_/64);
  const dim3 pool_grid((RN_+63)/64, POOL_/64, B_);

  // ---- intra path ----
  hipMemsetAsync(Sbuf, 0, (size_t)B_*R_*F_*sizeof(float), stream);
  gemm256<0,1><<<gemm_grid, 256, 0, stream>>>(x, w_mlp, b_mlp, bufA);          // h1
  colsum_k<<<dim3(B_*R_, 7), 256, 0, stream>>>(bufA, Sbuf, N_, 56);
  combine_k<0><<<M_*64/256, 256, 0, stream>>>(bufA, Sbuf, x, bufH);            // h
  gemm256<0,0><<<gemm_grid, 256, 0, stream>>>(bufH, k_gat, nullptr, bufA);     // xk
  st_k<<<M_/4, 256, 0, stream>>>(bufA, a_self, a_neigh, sbuf, tbuf);
  attn_intra_k<<<dim3(13, B_*R_), 256, 0, stream>>>(bufA, sbuf, tbuf, b_gat, bufH);
  pool_k<<<pool_grid, 256, 0, stream>>>(bufH, wa_pool, ba_pool, wf_pool, bf_pool, pooled, RN_);

  // ---- inter path ----
  hipMemsetAsync(Sbuf, 0, (size_t)B_*N_*F_*sizeof(float), stream);
  gemm256<1,1><<<gemm_grid, 256, 0, stream>>>(x, w_mlp, b_mlp, bufA);          // h1 (transposed view)
  colsum_k<<<dim3(B_*N_, 1), 256, 0, stream>>>(bufA, Sbuf, R_, 13);
  combine_k<1><<<M_*64/256, 256, 0, stream>>>(bufA, Sbuf, x, bufH);            // h2
  gemm256<0,0><<<gemm_grid, 256, 0, stream>>>(bufH, k_gat, nullptr, bufA);     // xk
  st_k<<<M_/4, 256, 0, stream>>>(bufA, a_self, a_neigh, sbuf, tbuf);
  attn_inter_k<<<B_*N_, 256, 0, stream>>>(bufA, sbuf, tbuf, b_gat, bufH);
  pool_k<<<pool_grid, 256, 0, stream>>>(bufH, wa_pool, ba_pool, wf_pool, bf_pool, pooled, RN_);

  // ---- classifier ----
  final_k<<<B_, 256, 0, stream>>>(pooled, bn_g, bn_b, bn_m, bn_v, w_out, b_out, out);
}

// Round 7
// 1127.705 us; speedup vs baseline: 2.4593x; 2.4593x over previous
//
#include <hip/hip_runtime.h>
#include <hip/hip_bf16.h>

#define B_    16
#define R_    13
#define N_    392
#define F_    256
#define RN_   (R_*N_)        // 5096
#define M_    (B_*RN_)       // 81536
#define POOL_ 512
#define NCLS_ 200

typedef __attribute__((ext_vector_type(4))) float f32x4;
typedef __attribute__((ext_vector_type(8))) short bf16x8;
typedef __attribute__((ext_vector_type(8))) unsigned short u16x8;

__device__ __forceinline__ unsigned short f2b(float f){
  union { float f; unsigned u; } v; v.f = f;
  unsigned r = v.u + 0x7FFF + ((v.u >> 16) & 1);   // RNE
  return (unsigned short)(r >> 16);
}
__device__ __forceinline__ float b2f(unsigned short b){
  union { unsigned u; float f; } v; v.u = ((unsigned)b) << 16;
  return v.f;
}

// ---------------- reduction helpers ----------------
__device__ __forceinline__ float warpMax(float v){
  #pragma unroll
  for (int o = 32; o; o >>= 1) v = fmaxf(v, __shfl_down(v, o));
  return v;
}
__device__ __forceinline__ float warpSum(float v){
  #pragma unroll
  for (int o = 32; o; o >>= 1) v += __shfl_down(v, o);
  return v;
}
__device__ __forceinline__ float blockMax(float v, float* red){
  v = warpMax(v);
  __syncthreads();
  if ((threadIdx.x & 63) == 0) red[threadIdx.x >> 6] = v;
  __syncthreads();
  return fmaxf(fmaxf(red[0], red[1]), fmaxf(red[2], red[3]));
}
__device__ __forceinline__ float blockSum(float v, float* red){
  v = warpSum(v);
  __syncthreads();
  if ((threadIdx.x & 63) == 0) red[threadIdx.x >> 6] = v;
  __syncthreads();
  return red[0] + red[1] + red[2] + red[3];
}
__device__ __forceinline__ float eluf(float v){
  return v > 0.f ? v : (expf(v) - 1.f);
}

// ---------------- weight transpose+convert: W[K,N] fp32 -> Wt[N,K] bf16 ----------------
__global__ __launch_bounds__(256) void cvt_wt(const float* __restrict__ W,
    unsigned short* __restrict__ Wt, int K, int N){
  const int id = blockIdx.x*256 + threadIdx.x;
  if (id < K*N){
    const int n = id / K, k = id - n*K;
    Wt[id] = f2b(W[k*N + n]);
  }
}

// ---------------- x fp32 -> bf16 (identity layout), 8 elems/thread ----------------
__global__ __launch_bounds__(256) void cvt_x(const float* __restrict__ x,
    unsigned short* __restrict__ xb){
  const long t = (long)blockIdx.x*256 + threadIdx.x;
  const float4 a = *(const float4*)&x[t*8];
  const float4 b = *(const float4*)&x[t*8 + 4];
  u16x8 o = {f2b(a.x),f2b(a.y),f2b(a.z),f2b(a.w),f2b(b.x),f2b(b.y),f2b(b.z),f2b(b.w)};
  *(u16x8*)&xb[t*8] = o;
}

// ---------------- x fp32 -> bf16 transposed view: row (b*N+n)*R+r <- phys (b*R+r)*N+n ----
__global__ __launch_bounds__(256) void cvt_xT(const float* __restrict__ x,
    unsigned short* __restrict__ xb){
  const long t = (long)blockIdx.x*256 + threadIdx.x;  // one 8-col chunk
  const int l  = (int)(t >> 5);
  const int c8 = ((int)t & 31) * 8;
  const int b  = l / RN_;
  const int rem = l - b*RN_;
  const int n  = rem / R_;
  const int r  = rem - n*R_;
  const long prow = (long)(b*R_ + r)*N_ + n;
  const float4 a  = *(const float4*)&x[prow*F_ + c8];
  const float4 bb = *(const float4*)&x[prow*F_ + c8 + 4];
  u16x8 o = {f2b(a.x),f2b(a.y),f2b(a.z),f2b(a.w),f2b(bb.x),f2b(bb.y),f2b(bb.z),f2b(bb.w)};
  *(u16x8*)&xb[(long)l*F_ + c8] = o;
}

// ---------------- MFMA GEMM: out[M,256] = A[M,256]bf16 @ Wt[256,256]^T bf16 ----------------
// Block 256 thr = 4 waves (2x2); tile 128x64; BK=64; ACT=1: sigmoid(acc+bias).
// A/B frags: 8 contiguous k per lane (row/col = lane&15, kgrp = lane>>4).
// C/D: row=(lane>>4)*4+q, col=lane&15  [verified layout, learn_hip m89/m91]
template<int ACT>
__global__ __launch_bounds__(256) void mfma_gemm(
    const unsigned short* __restrict__ A, const unsigned short* __restrict__ Wt,
    const float* __restrict__ bias, unsigned short* __restrict__ out){
  __shared__ unsigned short A_lds[128][72];   // pad 64->72 kills stride-128B conflicts
  __shared__ unsigned short W_lds[64][72];
  const int tid = threadIdx.x;
  const int lane = tid & 63, wid = tid >> 6;
  const int wr = wid >> 1, wc = wid & 1;
  const int lr = lane & 15, lk = lane >> 4;
  const int row0 = blockIdx.x * 128;
  const int col0 = blockIdx.y * 64;

  f32x4 acc[4][2] = {};
  for (int k0 = 0; k0 < 256; k0 += 64){
    #pragma unroll
    for (int i = 0; i < 4; ++i){
      const int chunk = tid + i*256;
      const int r = chunk >> 3, c8 = (chunk & 7)*8;
      *(u16x8*)&A_lds[r][c8] = *(const u16x8*)&A[(long)(row0 + r)*F_ + k0 + c8];
    }
    #pragma unroll
    for (int i = 0; i < 2; ++i){
      const int chunk = tid + i*256;
      const int r = chunk >> 3, c8 = (chunk & 7)*8;
      *(u16x8*)&W_lds[r][c8] = *(const u16x8*)&Wt[(long)(col0 + r)*F_ + k0 + c8];
    }
    __syncthreads();
    #pragma unroll
    for (int kk = 0; kk < 64; kk += 32){
      bf16x8 af[4], bf[2];
      #pragma unroll
      for (int m = 0; m < 4; ++m)
        af[m] = *(const bf16x8*)&A_lds[wr*64 + m*16 + lr][kk + lk*8];
      #pragma unroll
      for (int n = 0; n < 2; ++n)
        bf[n] = *(const bf16x8*)&W_lds[wc*32 + n*16 + lr][kk + lk*8];
      #pragma unroll
      for (int m = 0; m < 4; ++m)
        #pragma unroll
        for (int n = 0; n < 2; ++n)
          acc[m][n] = __builtin_amdgcn_mfma_f32_16x16x32_bf16(af[m], bf[n], acc[m][n], 0, 0, 0);
    }
    __syncthreads();
  }
  #pragma unroll
  for (int m = 0; m < 4; ++m){
    const int gr = row0 + wr*64 + m*16 + lk*4;
    #pragma unroll
    for (int n = 0; n < 2; ++n){
      const int gc = col0 + wc*32 + n*16 + lr;
      #pragma unroll
      for (int q = 0; q < 4; ++q){
        float v = acc[m][n][q];
        if (ACT) v = 1.f/(1.f + expf(-(v + bias[gc])));
        out[(long)(gr + q)*F_ + gc] = f2b(v);
      }
    }
  }
}

// ---------------- per-graph column sum (APPNP), direct store ----------------
__global__ __launch_bounds__(256) void colsum_k(const unsigned short* __restrict__ h1,
    float* __restrict__ S, int nn){
  const int g = blockIdx.x;
  const int f = threadIdx.x;
  const unsigned short* base = h1 + (long)g*nn*F_ + f;
  float s = 0.f;
  for (int n = 0; n < nn; ++n) s += b2f(base[(long)n*F_]);
  S[(long)g*F_ + f] = s;
}

// ---------------- h = 0.5*(S+h1)/(nn+1) + 0.5*h1 + x  (fp32 out + bf16 out) ----------------
template<int XMODE>
__global__ __launch_bounds__(256) void combine_k(const unsigned short* __restrict__ h1,
    const float* __restrict__ S, const float* __restrict__ x,
    float* __restrict__ h, unsigned short* __restrict__ hb){
  const long t = (long)blockIdx.x*256 + threadIdx.x;   // 4-elem groups
  const long row = t >> 6;
  const int f4 = ((int)t & 63) * 4;
  int g, xrow;
  if (XMODE == 0){ g = (int)(row / N_); xrow = (int)row; }
  else {
    g = (int)(row / R_);
    const int b   = (int)(row / RN_);
    const int rem = (int)(row - (long)b*RN_);
    const int n   = rem / R_;
    const int r   = rem - n*R_;
    xrow = (b*R_ + r)*N_ + n;
  }
  const float inv = (XMODE == 0) ? (1.f/(N_+1)) : (1.f/(R_+1));
  const ushort4 hraw = *(const ushort4*)&h1[row*F_ + f4];
  const float4 h1v = {b2f(hraw.x), b2f(hraw.y), b2f(hraw.z), b2f(hraw.w)};
  const float4 Sv  = *(const float4*)&S[(long)g*F_ + f4];
  const float4 xv  = *(const float4*)&x[(long)xrow*F_ + f4];
  float4 o;
  o.x = 0.5f*(Sv.x + h1v.x)*inv + 0.5f*h1v.x + xv.x;
  o.y = 0.5f*(Sv.y + h1v.y)*inv + 0.5f*h1v.y + xv.y;
  o.z = 0.5f*(Sv.z + h1v.z)*inv + 0.5f*h1v.z + xv.z;
  o.w = 0.5f*(Sv.w + h1v.w)*inv + 0.5f*h1v.w + xv.w;
  *(float4*)&h[row*F_ + f4] = o;
  const ushort4 ob = {f2b(o.x), f2b(o.y), f2b(o.z), f2b(o.w)};
  *(ushort4*)&hb[row*F_ + f4] = ob;
}

// ---------------- per-node attention scalars s,t (bf16 xk) ----------------
__global__ __launch_bounds__(256) void st_k(const unsigned short* __restrict__ xk,
    const float* __restrict__ a_self, const float* __restrict__ a_neigh,
    float* __restrict__ sv, float* __restrict__ tv){
  const int lane = threadIdx.x & 63;
  const int wid  = threadIdx.x >> 6;
  const long row = (long)blockIdx.x*4 + wid;
  const ushort4 raw = *(const ushort4*)&xk[row*F_ + lane*4];
  const float4 v  = {b2f(raw.x), b2f(raw.y), b2f(raw.z), b2f(raw.w)};
  const float4 as = *(const float4*)&a_self[lane*4];
  const float4 an = *(const float4*)&a_neigh[lane*4];
  float s = v.x*as.x + v.y*as.y + v.z*as.z + v.w*as.w;
  float t = v.x*an.x + v.y*an.y + v.z*an.z + v.w*an.w;
  #pragma unroll
  for (int o = 32; o; o >>= 1){ s += __shfl_down(s, o); t += __shfl_down(t, o); }
  if (lane == 0){ sv[row] = s; tv[row] = t; }
}

// ---------------- intra-ROI attention (graphs of 392): bf16 xk in, fp32 h, bf16 x2 out ----
__global__ __launch_bounds__(256) void attn_intra_k(
    const unsigned short* __restrict__ xk, const float* __restrict__ sv,
    const float* __restrict__ tv, const float* __restrict__ bg,
    const float* __restrict__ h, unsigned short* __restrict__ x2){
  const int g  = blockIdx.y;
  const int m0 = blockIdx.x * 32;
  const int tid = threadIdx.x;
  __shared__ float t_lds[N_];
  __shared__ float w_lds[32][N_];
  __shared__ float invr[32];
  __shared__ float red[4];

  for (int n = tid; n < N_; n += 256) t_lds[n] = tv[(long)g*N_ + n];
  __syncthreads();
  float tl = -1e30f;
  for (int n = tid; n < N_; n += 256) tl = fmaxf(tl, t_lds[n]);
  const float tmax = blockMax(tl, red);

  const int nrows = min(32, N_ - m0);
  for (int j = 0; j < nrows; ++j){
    const float sm = sv[(long)g*N_ + m0 + j];
    float zm = sm + tmax; zm = zm > 0.f ? zm : 0.2f*zm;   // lrelu monotone
    float loc = 0.f;
    for (int n = tid; n < N_; n += 256){
      float z = sm + t_lds[n];
      z = z > 0.f ? z : 0.2f*z;
      const float e = expf(z - zm);
      w_lds[j][n] = e;
      loc += e;
    }
    const float tot = blockSum(loc, red);
    if (tid == 0) invr[j] = 1.f / tot;
  }
  __syncthreads();

  const int ty = tid >> 6, tx = tid & 63;
  float4 acc[8];
  #pragma unroll
  for (int j = 0; j < 8; ++j) acc[j] = make_float4(0.f,0.f,0.f,0.f);
  const unsigned short* xkg = xk + (long)g*N_*F_;
  for (int n = 0; n < N_; ++n){
    const ushort4 raw = *(const ushort4*)&xkg[n*F_ + tx*4];
    const float4 xv = {b2f(raw.x), b2f(raw.y), b2f(raw.z), b2f(raw.w)};
    #pragma unroll
    for (int j = 0; j < 8; ++j){
      const float w = w_lds[ty*8 + j][n];
      acc[j].x += w*xv.x; acc[j].y += w*xv.y; acc[j].z += w*xv.z; acc[j].w += w*xv.w;
    }
  }
  const float4 bgv = *(const float4*)&bg[tx*4];
  #pragma unroll
  for (int j = 0; j < 8; ++j){
    const int m = m0 + ty*8 + j;
    if (m < N_){
      const float iv = invr[ty*8 + j];
      const long row = (long)g*N_ + m;
      const float4 hv = *(const float4*)&h[row*F_ + tx*4];
      ushort4 o;
      o.x = f2b(eluf(acc[j].x*iv + bgv.x) + hv.x);
      o.y = f2b(eluf(acc[j].y*iv + bgv.y) + hv.y);
      o.z = f2b(eluf(acc[j].z*iv + bgv.z) + hv.z);
      o.w = f2b(eluf(acc[j].w*iv + bgv.w) + hv.w);
      *(ushort4*)&x2[row*F_ + tx*4] = o;
    }
  }
}

// ---------------- inter-ROI attention (graphs of 13) ----------------
__global__ __launch_bounds__(256) void attn_inter_k(
    const unsigned short* __restrict__ xk, const float* __restrict__ sv,
    const float* __restrict__ tv, const float* __restrict__ bg,
    const float* __restrict__ h, unsigned short* __restrict__ x2){
  const int g = blockIdx.x;
  const int tid = threadIdx.x;
  __shared__ float w_lds[R_][R_];
  __shared__ float invr[R_];
  __shared__ float st[R_], tt[R_];
  if (tid < R_){ st[tid] = sv[(long)g*R_ + tid]; tt[tid] = tv[(long)g*R_ + tid]; }
  __syncthreads();
  if (tid < R_){
    const float sm = st[tid];
    float z[R_];
    float zm = -1e30f;
    #pragma unroll
    for (int n = 0; n < R_; ++n){
      float zz = sm + tt[n];
      zz = zz > 0.f ? zz : 0.2f*zz;
      z[n] = zz;
      zm = fmaxf(zm, zz);
    }
    float sum = 0.f;
    #pragma unroll
    for (int n = 0; n < R_; ++n){
      const float e = expf(z[n] - zm);
      w_lds[tid][n] = e;
      sum += e;
    }
    invr[tid] = 1.f/sum;
  }
  __syncthreads();
  float acc[R_] = {};
  const unsigned short* xkg = xk + (long)g*R_*F_;
  #pragma unroll
  for (int n = 0; n < R_; ++n){
    const float xv = b2f(xkg[n*F_ + tid]);
    #pragma unroll
    for (int m = 0; m < R_; ++m) acc[m] += w_lds[m][n]*xv;
  }
  const float bgv = bg[tid];
  #pragma unroll
  for (int m = 0; m < R_; ++m){
    const long row = (long)g*R_ + m;
    const float hv = h[row*F_ + tid];
    x2[row*F_ + tid] = f2b(eluf(acc[m]*invr[m] + bgv) + hv);
  }
}

// ---------------- pooling: dual MFMA GEMM + sigmoid-gate + j-reduce ----------------
// grid (40 j-tiles, 8 c-tiles, 16 batches); tile 128x64; two acc sets (attn/feat)
__global__ __launch_bounds__(256) void pool_mfma(
    const unsigned short* __restrict__ x2, const unsigned short* __restrict__ wat,
    const unsigned short* __restrict__ wft, const float* __restrict__ ba,
    const float* __restrict__ bfp, float* __restrict__ pooled){
  __shared__ unsigned short A_lds[128][72];
  __shared__ unsigned short Wa_lds[64][72];
  __shared__ unsigned short Wf_lds[64][72];
  __shared__ float redp[8][64];
  const int tid = threadIdx.x;
  const int lane = tid & 63, wid = tid >> 6;
  const int wr = wid >> 1, wc = wid & 1;
  const int lr = lane & 15, lk = lane >> 4;
  const int j0 = blockIdx.x * 128;
  const int c0 = blockIdx.y * 64;
  const int b  = blockIdx.z;
  const unsigned short* xb = x2 + (long)b * RN_ * F_;

  f32x4 accA[4][2] = {}, accF[4][2] = {};
  for (int k0 = 0; k0 < 256; k0 += 64){
    #pragma unroll
    for (int i = 0; i < 4; ++i){
      const int chunk = tid + i*256;
      const int r = chunk >> 3, c8 = (chunk & 7)*8;
      u16x8 v = {};
      if (j0 + r < RN_) v = *(const u16x8*)&xb[(long)(j0 + r)*F_ + k0 + c8];
      *(u16x8*)&A_lds[r][c8] = v;
    }
    #pragma unroll
    for (int i = 0; i < 2; ++i){
      const int chunk = tid + i*256;
      const int r = chunk >> 3, c8 = (chunk & 7)*8;
      *(u16x8*)&Wa_lds[r][c8] = *(const u16x8*)&wat[(long)(c0 + r)*F_ + k0 + c8];
      *(u16x8*)&Wf_lds[r][c8] = *(const u16x8*)&wft[(long)(c0 + r)*F_ + k0 + c8];
    }
    __syncthreads();
    #pragma unroll
    for (int kk = 0; kk < 64; kk += 32){
      bf16x8 af[4], bfa[2], bff[2];
      #pragma unroll
      for (int m = 0; m < 4; ++m)
        af[m] = *(const bf16x8*)&A_lds[wr*64 + m*16 + lr][kk + lk*8];
      #pragma unroll
      for (int n = 0; n < 2; ++n){
        bfa[n] = *(const bf16x8*)&Wa_lds[wc*32 + n*16 + lr][kk + lk*8];
        bff[n] = *(const bf16x8*)&Wf_lds[wc*32 + n*16 + lr][kk + lk*8];
      }
      #pragma unroll
      for (int m = 0; m < 4; ++m)
        #pragma unroll
        for (int n = 0; n < 2; ++n){
          accA[m][n] = __builtin_amdgcn_mfma_f32_16x16x32_bf16(af[m], bfa[n], accA[m][n], 0, 0, 0);
          accF[m][n] = __builtin_amdgcn_mfma_f32_16x16x32_bf16(af[m], bff[n], accF[m][n], 0, 0, 0);
        }
    }
    __syncthreads();
  }
  float csum[2] = {0.f, 0.f};
  #pragma unroll
  for (int m = 0; m < 4; ++m){
    const int jb = wr*64 + m*16 + lk*4;
    #pragma unroll
    for (int q = 0; q < 4; ++q){
      if (j0 + jb + q < RN_){
        #pragma unroll
        for (int n = 0; n < 2; ++n){
          const int c = c0 + wc*32 + n*16 + lr;
          const float a = accA[m][n][q] + ba[c];
          const float f = accF[m][n][q] + bfp[c];
          csum[n] += f / (1.f + expf(-a));
        }
      }
    }
  }
  #pragma unroll
  for (int n = 0; n < 2; ++n) redp[wr*4 + lk][wc*32 + n*16 + lr] = csum[n];
  __syncthreads();
  if (tid < 64){
    float s = 0.f;
    #pragma unroll
    for (int i = 0; i < 8; ++i) s += redp[i][tid];
    atomicAdd(&pooled[(long)b*POOL_ + c0 + tid], s);
  }
}

// ---------------- BN + classifier + softmax ----------------
__global__ __launch_bounds__(256) void final_k(const float* __restrict__ pooled,
    const float* __restrict__ gamma, const float* __restrict__ beta,
    const float* __restrict__ mean, const float* __restrict__ var,
    const float* __restrict__ wout, const float* __restrict__ bout,
    float* __restrict__ out){
  const int b = blockIdx.x, tid = threadIdx.x;
  __shared__ float bn[POOL_];
  __shared__ float red[4];
  for (int c = tid; c < POOL_; c += 256){
    const float p = pooled[(long)b*POOL_ + c];
    bn[c] = (p - mean[c]) * rsqrtf(var[c] + 1e-3f) * gamma[c] + beta[c];
  }
  __syncthreads();
  float logit = -3.0e38f;
  if (tid < NCLS_){
    float s = bout[tid];
    for (int k = 0; k < POOL_; ++k) s += bn[k]*wout[k*NCLS_ + tid];
    logit = s;
  }
  const float mx = blockMax(logit, red);
  float e = (tid < NCLS_) ? expf(logit - mx) : 0.f;
  const float tot = blockSum(e, red);
  if (tid < NCLS_) out[(long)b*NCLS_ + tid] = e / tot;
}

// ---------------- launcher ----------------
extern "C" void kernel_launch(void* const* d_in, const int* in_sizes, int n_in,
                              void* d_out, int out_size, void* d_ws, size_t ws_size,
                              hipStream_t stream){
  const float* x       = (const float*)d_in[0];
  const float* w_mlp   = (const float*)d_in[1];
  const float* b_mlp   = (const float*)d_in[2];
  const float* k_gat   = (const float*)d_in[3];
  const float* a_self  = (const float*)d_in[4];
  const float* a_neigh = (const float*)d_in[5];
  const float* b_gat   = (const float*)d_in[6];
  const float* wf_pool = (const float*)d_in[7];
  const float* bf_pool = (const float*)d_in[8];
  const float* wa_pool = (const float*)d_in[9];
  const float* ba_pool = (const float*)d_in[10];
  const float* bn_g    = (const float*)d_in[11];
  const float* bn_b    = (const float*)d_in[12];
  const float* bn_m    = (const float*)d_in[13];
  const float* bn_v    = (const float*)d_in[14];
  const float* w_out   = (const float*)d_in[15];
  const float* b_out   = (const float*)d_in[16];
  float* out = (float*)d_out;

  // Workspace (174.9 MB):
  //   abuf bf16 [M,F]: h1 then xk        hbuf fp32 [M,F]: h (residual)
  //   xbuf bf16 [M,F]: x_bf -> h_bf -> x2_bf (lifetime-disjoint)
  //   wt bf16: w_mlp^T, k_gat^T, wa^T, wf^T    Sbuf fp32 [B*N,F]   s,t [M]   pooled [B,512]
  char* p = (char*)d_ws;
  const long MF = (long)M_ * F_;
  unsigned short* abuf = (unsigned short*)p;  p += MF*2;
  float*          hbuf = (float*)p;           p += MF*4;
  unsigned short* xbuf = (unsigned short*)p;  p += MF*2;
  unsigned short* wmt  = (unsigned short*)p;  p += 65536*2;
  unsigned short* kgt  = (unsigned short*)p;  p += 65536*2;
  unsigned short* wat  = (unsigned short*)p;  p += 131072*2;
  unsigned short* wft  = (unsigned short*)p;  p += 131072*2;
  float*          Sbuf = (float*)p;           p += (long)B_*N_*F_*4;
  float*          sbuf = (float*)p;           p += (long)M_*4;
  float*          tbuf = (float*)p;           p += (long)M_*4;
  float*          pooled = (float*)p;         p += (long)B_*POOL_*4;

  hipMemsetAsync(pooled, 0, (size_t)B_*POOL_*sizeof(float), stream);

  cvt_wt<<<256, 256, 0, stream>>>(w_mlp,   wmt, 256, 256);
  cvt_wt<<<256, 256, 0, stream>>>(k_gat,   kgt, 256, 256);
  cvt_wt<<<512, 256, 0, stream>>>(wa_pool, wat, 256, 512);
  cvt_wt<<<512, 256, 0, stream>>>(wf_pool, wft, 256, 512);

  const dim3 ggrid(M_/128, F_/64);                  // (637, 4)
  const dim3 pgrid((RN_+127)/128, POOL_/64, B_);    // (40, 8, 16)

  // ---- intra path ----
  cvt_x<<<M_*F_/2048, 256, 0, stream>>>(x, xbuf);
  mfma_gemm<1><<<ggrid, 256, 0, stream>>>(xbuf, wmt, b_mlp, abuf);            // h1
  colsum_k<<<B_*R_, 256, 0, stream>>>(abuf, Sbuf, N_);
  combine_k<0><<<M_*64/256, 256, 0, stream>>>(abuf, Sbuf, x, hbuf, xbuf);     // h + h_bf
  mfma_gemm<0><<<ggrid, 256, 0, stream>>>(xbuf, kgt, nullptr, abuf);          // xk
  st_k<<<M_/4, 256, 0, stream>>>(abuf, a_self, a_neigh, sbuf, tbuf);
  attn_intra_k<<<dim3(13, B_*R_), 256, 0, stream>>>(abuf, sbuf, tbuf, b_gat, hbuf, xbuf);
  pool_mfma<<<pgrid, 256, 0, stream>>>(xbuf, wat, wft, ba_pool, bf_pool, pooled);

  // ---- inter path ----
  cvt_xT<<<M_*F_/2048, 256, 0, stream>>>(x, xbuf);
  mfma_gemm<1><<<ggrid, 256, 0, stream>>>(xbuf, wmt, b_mlp, abuf);            // h1 (transposed view)
  colsum_k<<<B_*N_, 256, 0, stream>>>(abuf, Sbuf, R_);
  combine_k<1><<<M_*64/256, 256, 0, stream>>>(abuf, Sbuf, x, hbuf, xbuf);     // h2 + h2_bf
  mfma_gemm<0><<<ggrid, 256, 0, stream>>>(xbuf, kgt, nullptr, abuf);          // xk
  st_k<<<M_/4, 256, 0, stream>>>(abuf, a_self, a_neigh, sbuf, tbuf);
  attn_inter_k<<<B_*N_, 256, 0, stream>>>(abuf, sbuf, tbuf, b_gat, hbuf, xbuf);
  pool_mfma<<<pgrid, 256, 0, stream>>>(xbuf, wat, wft, ba_pool, bf_pool, pooled);

  // ---- classifier ----
  final_k<<<B_, 256, 0, stream>>>(pooled, bn_g, bn_b, bn_m, bn_v, w_out, b_out, out);
}

// Round 14
// 959.506 us; speedup vs baseline: 2.8904x; 1.1753x over previous
//
#include <hip/hip_runtime.h>
#include <hip/hip_bf16.h>

#define B_    16
#define R_    13
#define N_    392
#define F_    256
#define RN_   (R_*N_)        // 5096
#define M_    (B_*RN_)       // 81536
#define POOL_ 512
#define NCLS_ 200
#define KP_   416            // N padded to 13*32 for MFMA K
#define WPS_  424            // Wp LDS stride (KP_+8 bank pad)

typedef __attribute__((ext_vector_type(4))) float f32x4;
typedef __attribute__((ext_vector_type(8))) short bf16x8;
typedef __attribute__((ext_vector_type(8))) unsigned short u16x8;

__device__ __forceinline__ unsigned short f2b(float f){
  union { float f; unsigned u; } v; v.f = f;
  unsigned r = v.u + 0x7FFF + ((v.u >> 16) & 1);   // RNE
  return (unsigned short)(r >> 16);
}
__device__ __forceinline__ float b2f(unsigned short b){
  union { unsigned u; float f; } v; v.u = ((unsigned)b) << 16;
  return v.f;
}

// ---------------- reduction helpers ----------------
__device__ __forceinline__ float warpMax(float v){
  #pragma unroll
  for (int o = 32; o; o >>= 1) v = fmaxf(v, __shfl_down(v, o));
  return v;
}
__device__ __forceinline__ float warpSum(float v){
  #pragma unroll
  for (int o = 32; o; o >>= 1) v += __shfl_down(v, o);
  return v;
}
__device__ __forceinline__ float blockMax(float v, float* red){
  v = warpMax(v);
  __syncthreads();
  if ((threadIdx.x & 63) == 0) red[threadIdx.x >> 6] = v;
  __syncthreads();
  return fmaxf(fmaxf(red[0], red[1]), fmaxf(red[2], red[3]));
}
__device__ __forceinline__ float blockSum(float v, float* red){
  v = warpSum(v);
  __syncthreads();
  if ((threadIdx.x & 63) == 0) red[threadIdx.x >> 6] = v;
  __syncthreads();
  return red[0] + red[1] + red[2] + red[3];
}
__device__ __forceinline__ float eluf(float v){
  return v > 0.f ? v : (expf(v) - 1.f);
}

// ---------------- weight transpose+convert: W[K,N] fp32 -> Wt[N,K] bf16 ----------------
__global__ __launch_bounds__(256) void cvt_wt(const float* __restrict__ W,
    unsigned short* __restrict__ Wt, int K, int N){
  const int id = blockIdx.x*256 + threadIdx.x;
  if (id < K*N){
    const int n = id / K, k = id - n*K;
    Wt[id] = f2b(W[k*N + n]);
  }
}

// ---------------- x fp32 -> bf16 (identity layout), 8 elems/thread ----------------
__global__ __launch_bounds__(256) void cvt_x(const float* __restrict__ x,
    unsigned short* __restrict__ xb){
  const long t = (long)blockIdx.x*256 + threadIdx.x;
  const float4 a = *(const float4*)&x[t*8];
  const float4 b = *(const float4*)&x[t*8 + 4];
  u16x8 o = {f2b(a.x),f2b(a.y),f2b(a.z),f2b(a.w),f2b(b.x),f2b(b.y),f2b(b.z),f2b(b.w)};
  *(u16x8*)&xb[t*8] = o;
}

// ---------------- x fp32 -> bf16 transposed view: row (b*N+n)*R+r <- phys (b*R+r)*N+n ----
__global__ __launch_bounds__(256) void cvt_xT(const float* __restrict__ x,
    unsigned short* __restrict__ xb){
  const long t = (long)blockIdx.x*256 + threadIdx.x;  // one 8-col chunk
  const int l  = (int)(t >> 5);
  const int c8 = ((int)t & 31) * 8;
  const int b  = l / RN_;
  const int rem = l - b*RN_;
  const int n  = rem / R_;
  const int r  = rem - n*R_;
  const long prow = (long)(b*R_ + r)*N_ + n;
  const float4 a  = *(const float4*)&x[prow*F_ + c8];
  const float4 bb = *(const float4*)&x[prow*F_ + c8 + 4];
  u16x8 o = {f2b(a.x),f2b(a.y),f2b(a.z),f2b(a.w),f2b(bb.x),f2b(bb.y),f2b(bb.z),f2b(bb.w)};
  *(u16x8*)&xb[(long)l*F_ + c8] = o;
}

// ---------------- MFMA GEMM: out[M,256] = A[M,256]bf16 @ Wt[256,256]^T bf16 ----------------
template<int ACT>
__global__ __launch_bounds__(256) void mfma_gemm(
    const unsigned short* __restrict__ A, const unsigned short* __restrict__ Wt,
    const float* __restrict__ bias, unsigned short* __restrict__ out){
  __shared__ unsigned short A_lds[128][72];
  __shared__ unsigned short W_lds[64][72];
  const int tid = threadIdx.x;
  const int lane = tid & 63, wid = tid >> 6;
  const int wr = wid >> 1, wc = wid & 1;
  const int lr = lane & 15, lk = lane >> 4;
  const int row0 = blockIdx.x * 128;
  const int col0 = blockIdx.y * 64;

  f32x4 acc[4][2] = {};
  for (int k0 = 0; k0 < 256; k0 += 64){
    #pragma unroll
    for (int i = 0; i < 4; ++i){
      const int chunk = tid + i*256;
      const int r = chunk >> 3, c8 = (chunk & 7)*8;
      *(u16x8*)&A_lds[r][c8] = *(const u16x8*)&A[(long)(row0 + r)*F_ + k0 + c8];
    }
    #pragma unroll
    for (int i = 0; i < 2; ++i){
      const int chunk = tid + i*256;
      const int r = chunk >> 3, c8 = (chunk & 7)*8;
      *(u16x8*)&W_lds[r][c8] = *(const u16x8*)&Wt[(long)(col0 + r)*F_ + k0 + c8];
    }
    __syncthreads();
    #pragma unroll
    for (int kk = 0; kk < 64; kk += 32){
      bf16x8 af[4], bf[2];
      #pragma unroll
      for (int m = 0; m < 4; ++m)
        af[m] = *(const bf16x8*)&A_lds[wr*64 + m*16 + lr][kk + lk*8];
      #pragma unroll
      for (int n = 0; n < 2; ++n)
        bf[n] = *(const bf16x8*)&W_lds[wc*32 + n*16 + lr][kk + lk*8];
      #pragma unroll
      for (int m = 0; m < 4; ++m)
        #pragma unroll
        for (int n = 0; n < 2; ++n)
          acc[m][n] = __builtin_amdgcn_mfma_f32_16x16x32_bf16(af[m], bf[n], acc[m][n], 0, 0, 0);
    }
    __syncthreads();
  }
  #pragma unroll
  for (int m = 0; m < 4; ++m){
    const int gr = row0 + wr*64 + m*16 + lk*4;
    #pragma unroll
    for (int n = 0; n < 2; ++n){
      const int gc = col0 + wc*32 + n*16 + lr;
      #pragma unroll
      for (int q = 0; q < 4; ++q){
        float v = acc[m][n][q];
        if (ACT) v = 1.f/(1.f + expf(-(v + bias[gc])));
        out[(long)(gr + q)*F_ + gc] = f2b(v);
      }
    }
  }
}

// ---------------- xk [g][392][256] -> xkT [g][256][416] bf16 (zero-padded K) ----------------
__global__ __launch_bounds__(256) void xkT_k(const unsigned short* __restrict__ xk,
    unsigned short* __restrict__ xkT){
  __shared__ unsigned short tile[32][36];
  const int n0 = blockIdx.x * 32;      // 0..12 -> covers 416
  const int f0 = blockIdx.y * 32;
  const int g  = blockIdx.z;
  const int t  = threadIdx.x;
  {
    const int nl = t >> 3, fl = (t & 7)*4;
    ushort4 v = {0,0,0,0};
    const int n = n0 + nl;
    if (n < N_) v = *(const ushort4*)&xk[((long)g*N_ + n)*F_ + f0 + fl];
    tile[nl][fl] = v.x; tile[nl][fl+1] = v.y; tile[nl][fl+2] = v.z; tile[nl][fl+3] = v.w;
  }
  __syncthreads();
  {
    const int fl = t >> 3, nl = (t & 7)*4;
    ushort4 o = {tile[nl][fl], tile[nl+1][fl], tile[nl+2][fl], tile[nl+3][fl]};
    *(ushort4*)&xkT[((long)g*F_ + f0 + fl)*KP_ + n0 + nl] = o;
  }
}

// ---------------- per-graph column sum (APPNP), direct store ----------------
__global__ __launch_bounds__(256) void colsum_k(const unsigned short* __restrict__ h1,
    float* __restrict__ S, int nn){
  const int g = blockIdx.x;
  const int f = threadIdx.x;
  const unsigned short* base = h1 + (long)g*nn*F_ + f;
  float s = 0.f;
  for (int n = 0; n < nn; ++n) s += b2f(base[(long)n*F_]);
  S[(long)g*F_ + f] = s;
}

// ---------------- h = 0.5*(S+h1)/(nn+1) + 0.5*h1 + x  (bf16 out) ----------------
template<int XMODE>
__global__ __launch_bounds__(256) void combine_k(const unsigned short* __restrict__ h1,
    const float* __restrict__ S, const float* __restrict__ x,
    unsigned short* __restrict__ hb){
  const long t = (long)blockIdx.x*256 + threadIdx.x;   // 4-elem groups
  const long row = t >> 6;
  const int f4 = ((int)t & 63) * 4;
  int g, xrow;
  if (XMODE == 0){ g = (int)(row / N_); xrow = (int)row; }
  else {
    g = (int)(row / R_);
    const int b   = (int)(row / RN_);
    const int rem = (int)(row - (long)b*RN_);
    const int n   = rem / R_;
    const int r   = rem - n*R_;
    xrow = (b*R_ + r)*N_ + n;
  }
  const float inv = (XMODE == 0) ? (1.f/(N_+1)) : (1.f/(R_+1));
  const ushort4 hraw = *(const ushort4*)&h1[row*F_ + f4];
  const float4 h1v = {b2f(hraw.x), b2f(hraw.y), b2f(hraw.z), b2f(hraw.w)};
  const float4 Sv  = *(const float4*)&S[(long)g*F_ + f4];
  const float4 xv  = *(const float4*)&x[(long)xrow*F_ + f4];
  float4 o;
  o.x = 0.5f*(Sv.x + h1v.x)*inv + 0.5f*h1v.x + xv.x;
  o.y = 0.5f*(Sv.y + h1v.y)*inv + 0.5f*h1v.y + xv.y;
  o.z = 0.5f*(Sv.z + h1v.z)*inv + 0.5f*h1v.z + xv.z;
  o.w = 0.5f*(Sv.w + h1v.w)*inv + 0.5f*h1v.w + xv.w;
  const ushort4 ob = {f2b(o.x), f2b(o.y), f2b(o.z), f2b(o.w)};
  *(ushort4*)&hb[row*F_ + f4] = ob;
}

// ---------------- per-node attention scalars s,t (bf16 xk) ----------------
__global__ __launch_bounds__(256) void st_k(const unsigned short* __restrict__ xk,
    const float* __restrict__ a_self, const float* __restrict__ a_neigh,
    float* __restrict__ sv, float* __restrict__ tv){
  const int lane = threadIdx.x & 63;
  const int wid  = threadIdx.x >> 6;
  const long row = (long)blockIdx.x*4 + wid;
  const ushort4 raw = *(const ushort4*)&xk[row*F_ + lane*4];
  const float4 v  = {b2f(raw.x), b2f(raw.y), b2f(raw.z), b2f(raw.w)};
  const float4 as = *(const float4*)&a_self[lane*4];
  const float4 an = *(const float4*)&a_neigh[lane*4];
  float s = v.x*as.x + v.y*as.y + v.z*as.z + v.w*as.w;
  float t = v.x*an.x + v.y*an.y + v.z*an.z + v.w*an.w;
  #pragma unroll
  for (int o = 32; o; o >>= 1){ s += __shfl_down(s, o); t += __shfl_down(t, o); }
  if (lane == 0){ sv[row] = s; tv[row] = t; }
}

// ---------------- intra-ROI attention (MFMA): P[64x392] @ Xk[392x256] per tile ----------------
// grid (7, 208); block 256 = 4 waves; wave w owns rows w*16..+15 (softmax) and cols w*64..+63 (MFMA).
// Unnormalized exp weights in LDS (bf16); row-normalization deferred to epilogue via invr.
// Residual read + x2 write IN PLACE on hx2 (same thread, same address).
__global__ __launch_bounds__(256) void attn_intra_k(
    const unsigned short* __restrict__ xkT, const float* __restrict__ sv,
    const float* __restrict__ tv, const float* __restrict__ bg,
    unsigned short* __restrict__ hx2){
  __shared__ unsigned short Wp[64][WPS_];
  __shared__ float t_lds[N_];
  __shared__ float s_lds[64];
  __shared__ float invr[64];
  __shared__ float red[4];
  const int g  = blockIdx.y;
  const int m0 = blockIdx.x * 64;
  const int tid = threadIdx.x;
  const int lane = tid & 63, wid = tid >> 6;

  for (int n = tid; n < N_; n += 256) t_lds[n] = tv[(long)g*N_ + n];
  if (tid < 64) s_lds[tid] = (m0 + tid < N_) ? sv[(long)g*N_ + m0 + tid] : 0.f;
  __syncthreads();
  float tl = -1e30f;
  for (int n = tid; n < N_; n += 256) tl = fmaxf(tl, t_lds[n]);
  const float tmax = blockMax(tl, red);

  // wave-parallel softmax: wave wid owns rows wid*16..+15
  for (int j = 0; j < 16; ++j){
    const int row = wid*16 + j;
    const float sm = s_lds[row];
    float zm = sm + tmax; zm = zm > 0.f ? zm : 0.2f*zm;   // lrelu monotone -> row max
    float loc = 0.f;
    for (int n = lane; n < KP_; n += 64){
      float e = 0.f;
      if (n < N_){
        float z = sm + t_lds[n];
        z = z > 0.f ? z : 0.2f*z;
        e = expf(z - zm);
        loc += e;
      }
      Wp[row][n] = f2b(e);
    }
    loc = warpSum(loc);
    if (lane == 0) invr[row] = 1.f / loc;
  }
  __syncthreads();

  // MFMA: out[64][256]; wave wid owns cols wid*64..+63
  const int lr = lane & 15, lk = lane >> 4;
  const int c0w = wid * 64;
  const unsigned short* xkTg = xkT + (long)g*F_*KP_;
  f32x4 acc[4][4] = {};
  for (int ks = 0; ks < 13; ++ks){
    const int k0 = ks*32;
    bf16x8 af[4], bfr[4];
    #pragma unroll
    for (int mi = 0; mi < 4; ++mi)
      af[mi] = *(const bf16x8*)&Wp[mi*16 + lr][k0 + lk*8];
    #pragma unroll
    for (int ni = 0; ni < 4; ++ni)
      bfr[ni] = *(const bf16x8*)&xkTg[(long)(c0w + ni*16 + lr)*KP_ + k0 + lk*8];
    #pragma unroll
    for (int mi = 0; mi < 4; ++mi)
      #pragma unroll
      for (int ni = 0; ni < 4; ++ni)
        acc[mi][ni] = __builtin_amdgcn_mfma_f32_16x16x32_bf16(af[mi], bfr[ni], acc[mi][ni], 0, 0, 0);
  }
  // epilogue: normalize, bias, elu, + residual (in place)
  #pragma unroll
  for (int mi = 0; mi < 4; ++mi){
    #pragma unroll
    for (int q = 0; q < 4; ++q){
      const int lm = mi*16 + lk*4 + q;
      const int m = m0 + lm;
      if (m < N_){
        const float iv = invr[lm];
        #pragma unroll
        for (int ni = 0; ni < 4; ++ni){
          const int f = c0w + ni*16 + lr;
          const long idx = ((long)g*N_ + m)*F_ + f;
          const float v = eluf(acc[mi][ni][q]*iv + bg[f]) + b2f(hx2[idx]);
          hx2[idx] = f2b(v);
        }
      }
    }
  }
}

// ---------------- inter-ROI attention (graphs of 13), in-place residual ----------------
__global__ __launch_bounds__(256) void attn_inter_k(
    const unsigned short* __restrict__ xk, const float* __restrict__ sv,
    const float* __restrict__ tv, const float* __restrict__ bg,
    unsigned short* __restrict__ hx2){
  const int g = blockIdx.x;
  const int tid = threadIdx.x;
  __shared__ float w_lds[R_][R_];
  __shared__ float invr[R_];
  __shared__ float st[R_], tt[R_];
  if (tid < R_){ st[tid] = sv[(long)g*R_ + tid]; tt[tid] = tv[(long)g*R_ + tid]; }
  __syncthreads();
  if (tid < R_){
    const float sm = st[tid];
    float z[R_];
    float zm = -1e30f;
    #pragma unroll
    for (int n = 0; n < R_; ++n){
      float zz = sm + tt[n];
      zz = zz > 0.f ? zz : 0.2f*zz;
      z[n] = zz;
      zm = fmaxf(zm, zz);
    }
    float sum = 0.f;
    #pragma unroll
    for (int n = 0; n < R_; ++n){
      const float e = expf(z[n] - zm);
      w_lds[tid][n] = e;
      sum += e;
    }
    invr[tid] = 1.f/sum;
  }
  __syncthreads();
  float acc[R_] = {};
  const unsigned short* xkg = xk + (long)g*R_*F_;
  #pragma unroll
  for (int n = 0; n < R_; ++n){
    const float xv = b2f(xkg[n*F_ + tid]);
    #pragma unroll
    for (int m = 0; m < R_; ++m) acc[m] += w_lds[m][n]*xv;
  }
  const float bgv = bg[tid];
  #pragma unroll
  for (int m = 0; m < R_; ++m){
    const long idx = ((long)g*R_ + m)*F_ + tid;
    const float hv = b2f(hx2[idx]);
    hx2[idx] = f2b(eluf(acc[m]*invr[m] + bgv) + hv);
  }
}

// ---------------- pooling: dual MFMA GEMM + sigmoid-gate + j-reduce ----------------
__global__ __launch_bounds__(256) void pool_mfma(
    const unsigned short* __restrict__ x2, const unsigned short* __restrict__ wat,
    const unsigned short* __restrict__ wft, const float* __restrict__ ba,
    const float* __restrict__ bfp, float* __restrict__ pooled){
  __shared__ unsigned short A_lds[128][72];
  __shared__ unsigned short Wa_lds[64][72];
  __shared__ unsigned short Wf_lds[64][72];
  __shared__ float redp[8][64];
  const int tid = threadIdx.x;
  const int lane = tid & 63, wid = tid >> 6;
  const int wr = wid >> 1, wc = wid & 1;
  const int lr = lane & 15, lk = lane >> 4;
  const int j0 = blockIdx.x * 128;
  const int c0 = blockIdx.y * 64;
  const int b  = blockIdx.z;
  const unsigned short* xb = x2 + (long)b * RN_ * F_;

  f32x4 accA[4][2] = {}, accF[4][2] = {};
  for (int k0 = 0; k0 < 256; k0 += 64){
    #pragma unroll
    for (int i = 0; i < 4; ++i){
      const int chunk = tid + i*256;
      const int r = chunk >> 3, c8 = (chunk & 7)*8;
      u16x8 v = {};
      if (j0 + r < RN_) v = *(const u16x8*)&xb[(long)(j0 + r)*F_ + k0 + c8];
      *(u16x8*)&A_lds[r][c8] = v;
    }
    #pragma unroll
    for (int i = 0; i < 2; ++i){
      const int chunk = tid + i*256;
      const int r = chunk >> 3, c8 = (chunk & 7)*8;
      *(u16x8*)&Wa_lds[r][c8] = *(const u16x8*)&wat[(long)(c0 + r)*F_ + k0 + c8];
      *(u16x8*)&Wf_lds[r][c8] = *(const u16x8*)&wft[(long)(c0 + r)*F_ + k0 + c8];
    }
    __syncthreads();
    #pragma unroll
    for (int kk = 0; kk < 64; kk += 32){
      bf16x8 af[4], bfa[2], bff[2];
      #pragma unroll
      for (int m = 0; m < 4; ++m)
        af[m] = *(const bf16x8*)&A_lds[wr*64 + m*16 + lr][kk + lk*8];
      #pragma unroll
      for (int n = 0; n < 2; ++n){
        bfa[n] = *(const bf16x8*)&Wa_lds[wc*32 + n*16 + lr][kk + lk*8];
        bff[n] = *(const bf16x8*)&Wf_lds[wc*32 + n*16 + lr][kk + lk*8];
      }
      #pragma unroll
      for (int m = 0; m < 4; ++m)
        #pragma unroll
        for (int n = 0; n < 2; ++n){
          accA[m][n] = __builtin_amdgcn_mfma_f32_16x16x32_bf16(af[m], bfa[n], accA[m][n], 0, 0, 0);
          accF[m][n] = __builtin_amdgcn_mfma_f32_16x16x32_bf16(af[m], bff[n], accF[m][n], 0, 0, 0);
        }
    }
    __syncthreads();
  }
  float csum[2] = {0.f, 0.f};
  #pragma unroll
  for (int m = 0; m < 4; ++m){
    const int jb = wr*64 + m*16 + lk*4;
    #pragma unroll
    for (int q = 0; q < 4; ++q){
      if (j0 + jb + q < RN_){
        #pragma unroll
        for (int n = 0; n < 2; ++n){
          const int c = c0 + wc*32 + n*16 + lr;
          const float a = accA[m][n][q] + ba[c];
          const float f = accF[m][n][q] + bfp[c];
          csum[n] += f / (1.f + expf(-a));
        }
      }
    }
  }
  #pragma unroll
  for (int n = 0; n < 2; ++n) redp[wr*4 + lk][wc*32 + n*16 + lr] = csum[n];
  __syncthreads();
  if (tid < 64){
    float s = 0.f;
    #pragma unroll
    for (int i = 0; i < 8; ++i) s += redp[i][tid];
    atomicAdd(&pooled[(long)b*POOL_ + c0 + tid], s);
  }
}

// ---------------- BN + classifier + softmax ----------------
__global__ __launch_bounds__(256) void final_k(const float* __restrict__ pooled,
    const float* __restrict__ gamma, const float* __restrict__ beta,
    const float* __restrict__ mean, const float* __restrict__ var,
    const float* __restrict__ wout, const float* __restrict__ bout,
    float* __restrict__ out){
  const int b = blockIdx.x, tid = threadIdx.x;
  __shared__ float bn[POOL_];
  __shared__ float red[4];
  for (int c = tid; c < POOL_; c += 256){
    const float p = pooled[(long)b*POOL_ + c];
    bn[c] = (p - mean[c]) * rsqrtf(var[c] + 1e-3f) * gamma[c] + beta[c];
  }
  __syncthreads();
  float logit = -3.0e38f;
  if (tid < NCLS_){
    float s = bout[tid];
    for (int k = 0; k < POOL_; ++k) s += bn[k]*wout[k*NCLS_ + tid];
    logit = s;
  }
  const float mx = blockMax(logit, red);
  float e = (tid < NCLS_) ? expf(logit - mx) : 0.f;
  const float tot = blockSum(e, red);
  if (tid < NCLS_) out[(long)b*NCLS_ + tid] = e / tot;
}

// ---------------- launcher ----------------
extern "C" void kernel_launch(void* const* d_in, const int* in_sizes, int n_in,
                              void* d_out, int out_size, void* d_ws, size_t ws_size,
                              hipStream_t stream){
  const float* x       = (const float*)d_in[0];
  const float* w_mlp   = (const float*)d_in[1];
  const float* b_mlp   = (const float*)d_in[2];
  const float* k_gat   = (const float*)d_in[3];
  const float* a_self  = (const float*)d_in[4];
  const float* a_neigh = (const float*)d_in[5];
  const float* b_gat   = (const float*)d_in[6];
  const float* wf_pool = (const float*)d_in[7];
  const float* bf_pool = (const float*)d_in[8];
  const float* wa_pool = (const float*)d_in[9];
  const float* ba_pool = (const float*)d_in[10];
  const float* bn_g    = (const float*)d_in[11];
  const float* bn_b    = (const float*)d_in[12];
  const float* bn_m    = (const float*)d_in[13];
  const float* bn_v    = (const float*)d_in[14];
  const float* w_out   = (const float*)d_in[15];
  const float* b_out   = (const float*)d_in[16];
  float* out = (float*)d_out;

  // Workspace (135.7 MB):
  //   abuf bf16 [M,F]: h1 then xk
  //   xbuf bf16 [M,F]: x_bf -> h_bf -> x2 (attn residual+write IN PLACE)
  //   xkT  bf16 [B*R][256][416]: transposed xk for attention B-operand (intra only)
  //   weights bf16, Sbuf fp32 [B*N,F], s/t [M], pooled [B,512]
  char* p = (char*)d_ws;
  const long MF = (long)M_ * F_;
  unsigned short* abuf = (unsigned short*)p;  p += MF*2;
  unsigned short* xbuf = (unsigned short*)p;  p += MF*2;
  unsigned short* xkT  = (unsigned short*)p;  p += (long)B_*R_*F_*KP_*2;
  unsigned short* wmt  = (unsigned short*)p;  p += 65536*2;
  unsigned short* kgt  = (unsigned short*)p;  p += 65536*2;
  unsigned short* wat  = (unsigned short*)p;  p += 131072*2;
  unsigned short* wft  = (unsigned short*)p;  p += 131072*2;
  float*          Sbuf = (float*)p;           p += (long)B_*N_*F_*4;
  float*          sbuf = (float*)p;           p += (long)M_*4;
  float*          tbuf = (float*)p;           p += (long)M_*4;
  float*          pooled = (float*)p;         p += (long)B_*POOL_*4;

  hipMemsetAsync(pooled, 0, (size_t)B_*POOL_*sizeof(float), stream);

  cvt_wt<<<256, 256, 0, stream>>>(w_mlp,   wmt, 256, 256);
  cvt_wt<<<256, 256, 0, stream>>>(k_gat,   kgt, 256, 256);
  cvt_wt<<<512, 256, 0, stream>>>(wa_pool, wat, 256, 512);
  cvt_wt<<<512, 256, 0, stream>>>(wf_pool, wft, 256, 512);

  const dim3 ggrid(M_/128, F_/64);                  // (637, 4)
  const dim3 pgrid((RN_+127)/128, POOL_/64, B_);    // (40, 8, 16)

  // ---- intra path ----
  cvt_x<<<M_*F_/2048, 256, 0, stream>>>(x, xbuf);
  mfma_gemm<1><<<ggrid, 256, 0, stream>>>(xbuf, wmt, b_mlp, abuf);            // h1
  colsum_k<<<B_*R_, 256, 0, stream>>>(abuf, Sbuf, N_);
  combine_k<0><<<M_*64/256, 256, 0, stream>>>(abuf, Sbuf, x, xbuf);           // h_bf (in xbuf)
  mfma_gemm<0><<<ggrid, 256, 0, stream>>>(xbuf, kgt, nullptr, abuf);          // xk
  xkT_k<<<dim3(KP_/32, F_/32, B_*R_), 256, 0, stream>>>(abuf, xkT);
  st_k<<<M_/4, 256, 0, stream>>>(abuf, a_self, a_neigh, sbuf, tbuf);
  attn_intra_k<<<dim3(7, B_*R_), 256, 0, stream>>>(xkT, sbuf, tbuf, b_gat, xbuf);
  pool_mfma<<<pgrid, 256, 0, stream>>>(xbuf, wat, wft, ba_pool, bf_pool, pooled);

  // ---- inter path ----
  cvt_xT<<<M_*F_/2048, 256, 0, stream>>>(x, xbuf);
  mfma_gemm<1><<<ggrid, 256, 0, stream>>>(xbuf, wmt, b_mlp, abuf);            // h1 (transposed view)
  colsum_k<<<B_*N_, 256, 0, stream>>>(abuf, Sbuf, R_);
  combine_k<1><<<M_*64/256, 256, 0, stream>>>(abuf, Sbuf, x, xbuf);           // h2_bf
  mfma_gemm<0><<<ggrid, 256, 0, stream>>>(xbuf, kgt, nullptr, abuf);          // xk
  st_k<<<M_/4, 256, 0, stream>>>(abuf, a_self, a_neigh, sbuf, tbuf);
  attn_inter_k<<<B_*N_, 256, 0, stream>>>(abuf, sbuf, tbuf, b_gat, xbuf);
  pool_mfma<<<pgrid, 256, 0, stream>>>(xbuf, wat, wft, ba_pool, bf_pool, pooled);

  // ---- classifier ----
  final_k<<<B_, 256, 0, stream>>>(pooled, bn_g, bn_b, bn_m, bn_v, w_out, b_out, out);
}